// Round 6
// baseline (321.568 us; speedup 1.0000x reference)
//
#include <hip/hip_runtime.h>

// Problem constants
#define B 8
#define N 4096
#define C 128
#define C2 256          // K-dim of fused GEMM: [ptl | s]
#define KNN 21          // top-(K+1), drop nearest
#define CAP 12          // per-lane append buffer capacity

typedef unsigned long long u64;
typedef unsigned int u32;
typedef unsigned short u16;

typedef __attribute__((ext_vector_type(8))) short bf16x8;
typedef __attribute__((ext_vector_type(4))) float f32x4;

__device__ __forceinline__ float bf2f(u16 u) {
    return __uint_as_float(((u32)u) << 16);
}
__device__ __forceinline__ u16 f2bf(float f) {  // round-to-nearest-even
    u32 x = __float_as_uint(f);
    return (u16)((x + 0x7FFFu + ((x >> 16) & 1u)) >> 16);
}

// ---------------------------------------------------------------------------
// K1: transpose + leaky_relu: points (B,C,N) f32 -> X[b][n][c] (c<128) bf16
// ---------------------------------------------------------------------------
__global__ __launch_bounds__(256) void k_transpose_lrelu(
        const float* __restrict__ pts, u16* __restrict__ X) {
    __shared__ u16 tile[32][33];
    int b  = blockIdx.z;
    int c0 = blockIdx.y * 32;
    int n0 = blockIdx.x * 32;
    int tx = threadIdx.x, ty = threadIdx.y;   // 32 x 8
    const float* src = pts + (size_t)b * C * N;
    #pragma unroll
    for (int i = 0; i < 32; i += 8) {
        float v = src[(size_t)(c0 + ty + i) * N + n0 + tx];
        if (v < 0.f) v = __fmul_rn(v, 0.01f);
        tile[ty + i][tx] = f2bf(v);
    }
    __syncthreads();
    u16* dst = X + (size_t)b * N * C2;
    #pragma unroll
    for (int i = 0; i < 32; i += 8) {
        dst[(size_t)(n0 + ty + i) * C2 + (c0 + tx)] = tile[tx][ty + i];
    }
}

// ---------------------------------------------------------------------------
// K2: exact KNN (top-21 by (sq, idx), drop min) + neighbor-feature gather-sum.
// Grid 1024 blocks (4/CU). Block = 32 queries, 256 thr = 4 waves.
// Lane l -> (query l>>1, candidate-half l&1): each lane scans 512 candidates
// from [w*1024 + h*512, +512). 8 sorted-21 lists per query merged by wave 0.
// Selection: u32 sortable key + parallel idx regs; strict compares preserve
// np top_k index tie-break; merge on lex-packed (key<<16|idx).
// ---------------------------------------------------------------------------
__global__ __launch_bounds__(256) void k_knn_gather(
        const float* __restrict__ xyz, u16* __restrict__ X) {
    __shared__ __align__(16) char lds[34816];
    float4* stg  = (float4*)lds;                      // [4][256]   16384 B
    u32*    kbuf = (u32*)(lds + 16384);               // [CAP][256] 12288 B
    u16*    ibuf = (u16*)(lds + 16384 + 12288);       // [CAP][256]  6144 B
    u32*    mk   = (u32*)lds;                         // [256][21]  21504 B (phase B)
    u16*    mi   = (u16*)(lds + 21504);               // [256][21]  10752 B (phase B)
    __shared__ u16 win[32 * KNN];

    int tid = threadIdx.x;
    int w = tid >> 6, l = tid & 63;
    int q = l >> 1, h = l & 1;
    int b = blockIdx.y;
    int n0 = blockIdx.x * 32;
    int nq = n0 + q;

    const float* xz = xyz + (size_t)b * 3 * N;
    // query point (np formula: ((x*x + y*y) + z*z))
    float qx = xz[nq], qy = xz[N + nq], qz = xz[2 * N + nq];
    float snq = __fadd_rn(__fadd_rn(__fmul_rn(qx, qx), __fmul_rn(qy, qy)),
                          __fmul_rn(qz, qz));

    u32 key[KNN], idx[KNN];
    #pragma unroll
    for (int i = 0; i < KNN; ++i) { key[i] = 0xFFFFFFFFu; idx[i] = 0u; }
    int cnt = 0;
    u32 thr = 0xFFFFFFFFu;

    auto compact = [&]() {
        #pragma unroll 1
        for (int i = 0; i < CAP; ++i) {
            if (__ballot(i < cnt) == 0ull) break;
            u32 kv = kbuf[i * 256 + tid];
            u32 iv = ibuf[i * 256 + tid];
            bool ins = (i < cnt) && (kv < key[20]);   // strict: ties keep old
            if (__ballot(ins) != 0ull) {
                key[20] = ins ? kv : key[20];
                idx[20] = ins ? iv : idx[20];
                #pragma unroll
                for (int t = 19; t >= 0; --t) {       // stable bubble (strict >)
                    bool sw = key[t] > key[t + 1];
                    u32 ka = sw ? key[t + 1] : key[t];
                    u32 kz = sw ? key[t] : key[t + 1];
                    u32 ia = sw ? idx[t + 1] : idx[t];
                    u32 iz = sw ? idx[t] : idx[t + 1];
                    key[t] = ka; key[t + 1] = kz;
                    idx[t] = ia; idx[t + 1] = iz;
                }
            }
        }
        cnt = 0;
        thr = key[20];
    };

    for (int sc = 0; sc < 4; ++sc) {
        // stage 2x128 candidates (x,y,z,sq_norm) for this wave's two halves
        #pragma unroll
        for (int r = 0; r < 4; ++r) {
            int e = l + 64 * r;                       // 0..255
            int he = e >> 7, je = e & 127;
            int m = w * 1024 + he * 512 + sc * 128 + je;
            float x = xz[m], y = xz[N + m], z = xz[2 * N + m];
            float sn = __fadd_rn(__fadd_rn(__fmul_rn(x, x), __fmul_rn(y, y)),
                                 __fmul_rn(z, z));
            stg[w * 256 + e] = make_float4(x, y, z, sn);
        }
        asm volatile("s_waitcnt lgkmcnt(0)" ::: "memory");
        int mbase = w * 1024 + h * 512 + sc * 128;
        const float4* mystg = stg + w * 256 + h * 128;
        for (int cc = 0; cc < 128; cc += 4) {
            #pragma unroll
            for (int u = 0; u < 4; ++u) {
                float4 cp = mystg[cc + u];            // 2-addr broadcast read
                int m = mbase + cc + u;
                float dot = __fadd_rn(__fadd_rn(__fmul_rn(qx, cp.x),
                                                __fmul_rn(qy, cp.y)),
                                      __fmul_rn(qz, cp.z));
                float sq = __fadd_rn(__fsub_rn(snq, __fadd_rn(dot, dot)), cp.w);
                u32 bits = __float_as_uint(sq);
                u32 kb = bits ^ (0x80000000u | (u32)(((int)bits) >> 31));
                kbuf[cnt * 256 + tid] = kb;           // unconditional append
                ibuf[cnt * 256 + tid] = (u16)m;
                cnt += (kb < thr);                    // strict: ties dropped
            }
            if (__ballot(cnt > 8) != 0ull) compact();
        }
    }
    compact();

    __syncthreads();                                  // phase-A buffers dead
    #pragma unroll
    for (int j = 0; j < KNN; ++j) {
        mk[(w * 64 + l) * KNN + j] = key[j];
        mi[(w * 64 + l) * KNN + j] = idx[j];
    }
    __syncthreads();

    if (w == 0 && l < 32) {                           // 8-way merge, query = l
        int p[1];                                     // pointers kept scalar:
        int p0 = 0, p1 = 0, p2 = 0, p3 = 0, p4 = 0, p5 = 0, p6 = 0, p7 = 0;
        (void)p;
        #pragma unroll 1
        for (int j = 0; j < KNN; ++j) {
            // list r = wave (r>>1), half (r&1) -> row (r>>1)*64 + l*2 + (r&1)
            #define LOADC(r, pr) \
                u64 c##r = ((u64)mk[(((r) >> 1) * 64 + l * 2 + ((r) & 1)) * KNN + pr] << 16) \
                         |  (u64)mi[(((r) >> 1) * 64 + l * 2 + ((r) & 1)) * KNN + pr];
            LOADC(0, p0) LOADC(1, p1) LOADC(2, p2) LOADC(3, p3)
            LOADC(4, p4) LOADC(5, p5) LOADC(6, p6) LOADC(7, p7)
            #undef LOADC
            u64 m01 = c0 < c1 ? c0 : c1; int s01 = c0 < c1 ? 0 : 1;
            u64 m23 = c2 < c3 ? c2 : c3; int s23 = c2 < c3 ? 2 : 3;
            u64 m45 = c4 < c5 ? c4 : c5; int s45 = c4 < c5 ? 4 : 5;
            u64 m67 = c6 < c7 ? c6 : c7; int s67 = c6 < c7 ? 6 : 7;
            u64 m03 = m01 < m23 ? m01 : m23; int s03 = m01 < m23 ? s01 : s23;
            u64 m47 = m45 < m67 ? m45 : m67; int s47 = m45 < m67 ? s45 : s67;
            u64 mm  = m03 < m47 ? m03 : m47; int sel = m03 < m47 ? s03 : s47;
            win[l * KNN + j] = (u16)(mm & 0xFFFFu);
            p0 += (sel == 0); p1 += (sel == 1); p2 += (sel == 2); p3 += (sel == 3);
            p4 += (sel == 4); p5 += (sel == 5); p6 += (sel == 6); p7 += (sel == 7);
        }
    }
    __syncthreads();

    // gather-sum: wave w handles 8 queries; lane covers channels 2l, 2l+1
    const u16* Xb = X + (size_t)b * N * C2;
    for (int qq = 0; qq < 8; ++qq) {
        int qg = w * 8 + qq;
        float f0 = 0.f, f1 = 0.f;
        #pragma unroll
        for (int j = 1; j < KNN; ++j) {               // skip nearest (j=0)
            int m = win[qg * KNN + j];
            u32 u2 = *(const u32*)(Xb + (size_t)m * C2 + 2 * l);
            f0 += bf2f((u16)(u2 & 0xFFFFu));
            f1 += bf2f((u16)(u2 >> 16));
        }
        u16* dst = X + ((size_t)b * N + n0 + qg) * C2 + 128 + 2 * l;
        *(u32*)dst = ((u32)f2bf(f1) << 16) | (u32)f2bf(f0);
    }
}

// ---------------------------------------------------------------------------
// K3: MFMA GEMM. out[b][o][n] = (W[o][:].X[b][n][:] + bc[o]+20bg[o])/21 + pts.
// Wave tile: 16(o) x 64(n), K=256 = 8 x mfma_f32_16x16x32_bf16 x 4 subtiles.
// A-frag loaded directly from Wc (kk<4) / Wg (kk>=4) fp32 rows, cvt f2bf.
// C/D map: col=lane&15 (n), row=(lane>>4)*4+reg (o)  [m89-verified]
// ---------------------------------------------------------------------------
__global__ __launch_bounds__(256) void k_gemm_mfma(
        const u16* __restrict__ X, const float* __restrict__ Wc,
        const float* __restrict__ Wg, const float* __restrict__ pts,
        const float* __restrict__ bc, const float* __restrict__ bg,
        float* __restrict__ out) {
    int wid = blockIdx.x * 4 + (threadIdx.x >> 6);   // 0..4095
    int lane = threadIdx.x & 63;
    int ot = wid & 7;            // 8 o-tiles of 16
    int nt = wid >> 3;           // 512 n-tiles of 64
    int b  = nt >> 6;            // 64 n-tiles per batch
    int n0 = (nt & 63) * 64;

    int l16 = lane & 15, lq = lane >> 4;
    const u16* Xb = X + (size_t)b * N * C2;
    const u16* bptr0 = Xb + (size_t)(n0 + 0 * 16 + l16) * C2 + lq * 8;
    const u16* bptr1 = Xb + (size_t)(n0 + 1 * 16 + l16) * C2 + lq * 8;
    const u16* bptr2 = Xb + (size_t)(n0 + 2 * 16 + l16) * C2 + lq * 8;
    const u16* bptr3 = Xb + (size_t)(n0 + 3 * 16 + l16) * C2 + lq * 8;
    const float* wrowc = Wc + (size_t)(ot * 16 + l16) * 128 + lq * 8;
    const float* wrowg = Wg + (size_t)(ot * 16 + l16) * 128 + lq * 8;

    f32x4 acc0 = {0.f, 0.f, 0.f, 0.f};
    f32x4 acc1 = {0.f, 0.f, 0.f, 0.f};
    f32x4 acc2 = {0.f, 0.f, 0.f, 0.f};
    f32x4 acc3 = {0.f, 0.f, 0.f, 0.f};
    #pragma unroll
    for (int kk = 0; kk < 8; ++kk) {
        const float* ws = (kk < 4) ? (wrowc + kk * 32) : (wrowg + (kk - 4) * 32);
        float4 wa = *(const float4*)ws;
        float4 wb = *(const float4*)(ws + 4);
        bf16x8 a;
        a[0] = (short)f2bf(wa.x); a[1] = (short)f2bf(wa.y);
        a[2] = (short)f2bf(wa.z); a[3] = (short)f2bf(wa.w);
        a[4] = (short)f2bf(wb.x); a[5] = (short)f2bf(wb.y);
        a[6] = (short)f2bf(wb.z); a[7] = (short)f2bf(wb.w);
        bf16x8 b0 = *(const bf16x8*)(bptr0 + kk * 32);
        bf16x8 b1 = *(const bf16x8*)(bptr1 + kk * 32);
        bf16x8 b2 = *(const bf16x8*)(bptr2 + kk * 32);
        bf16x8 b3 = *(const bf16x8*)(bptr3 + kk * 32);
        acc0 = __builtin_amdgcn_mfma_f32_16x16x32_bf16(a, b0, acc0, 0, 0, 0);
        acc1 = __builtin_amdgcn_mfma_f32_16x16x32_bf16(a, b1, acc1, 0, 0, 0);
        acc2 = __builtin_amdgcn_mfma_f32_16x16x32_bf16(a, b2, acc2, 0, 0, 0);
        acc3 = __builtin_amdgcn_mfma_f32_16x16x32_bf16(a, b3, acc3, 0, 0, 0);
    }

    const float inv21 = 1.0f / 21.0f;
    float bias[4];
    #pragma unroll
    for (int r = 0; r < 4; ++r) {
        int o = ot * 16 + lq * 4 + r;
        bias[r] = bc[o] + 20.f * bg[o];
    }
    const float* pb = pts + (size_t)b * C * N;
    float* ob = out + (size_t)b * C * N;
    f32x4 accs[4] = {acc0, acc1, acc2, acc3};
    #pragma unroll
    for (int t = 0; t < 4; ++t) {
        int n = n0 + t * 16 + l16;
        #pragma unroll
        for (int r = 0; r < 4; ++r) {
            int o = ot * 16 + lq * 4 + r;
            ob[(size_t)o * N + n] =
                (accs[t][r] + bias[r]) * inv21 + pb[(size_t)o * N + n];
        }
    }
}

// ---------------------------------------------------------------------------
extern "C" void kernel_launch(void* const* d_in, const int* in_sizes, int n_in,
                              void* d_out, int out_size, void* d_ws, size_t ws_size,
                              hipStream_t stream) {
    const float* xyz = (const float*)d_in[0];
    const float* pts = (const float*)d_in[1];
    const float* Wc  = (const float*)d_in[2];
    const float* bc  = (const float*)d_in[3];
    const float* Wg  = (const float*)d_in[4];
    const float* bg  = (const float*)d_in[5];
    float* out = (float*)d_out;

    u16* X = (u16*)d_ws;                              // B*N*C2 bf16 = 16 MB

    k_transpose_lrelu<<<dim3(N / 32, C / 32, B), dim3(32, 8), 0, stream>>>(pts, X);
    k_knn_gather<<<dim3(N / 32, B), dim3(256), 0, stream>>>(xyz, X);
    k_gemm_mfma<<<dim3(1024), dim3(256), 0, stream>>>(X, Wc, Wg, pts, bc, bg, out);
}